// Round 5
// baseline (523.023 us; speedup 1.0000x reference)
//
#include <hip/hip_runtime.h>
#include <cstdint>

static constexpr int N = 100000;
static constexpr int D = 64;
static constexpr int E = 1250000;
static constexpr float EPS = 1e-5f;

// ---------------- threefry2x32, 20 rounds, key = (0, 42) --------------------
__device__ __forceinline__ uint32_t rotl32(uint32_t x, int r) {
    return (x << r) | (x >> (32 - r));
}

__device__ __forceinline__ void threefry2x32_k42(uint32_t& x0, uint32_t& x1) {
    const uint32_t ks0 = 0u, ks1 = 42u, ks2 = 0x1BD11BDAu ^ 0u ^ 42u; // 0x1BD11BF0
    x0 += ks0; x1 += ks1;
#define TF_R4(a,b,c,d) \
    x0 += x1; x1 = rotl32(x1,a); x1 ^= x0; \
    x0 += x1; x1 = rotl32(x1,b); x1 ^= x0; \
    x0 += x1; x1 = rotl32(x1,c); x1 ^= x0; \
    x0 += x1; x1 = rotl32(x1,d); x1 ^= x0;
    TF_R4(13,15,26,6);  x0 += ks1; x1 += ks2 + 1u;
    TF_R4(17,29,16,24); x0 += ks2; x1 += ks0 + 2u;
    TF_R4(13,15,26,6);  x0 += ks0; x1 += ks1 + 3u;
    TF_R4(17,29,16,24); x0 += ks1; x1 += ks2 + 4u;
    TF_R4(13,15,26,6);  x0 += ks2; x1 += ks0 + 5u;
#undef TF_R4
}

// ---------------- edge_index dtype detection (int64 vs int32) ---------------
__global__ void k_detect(const uint32_t* __restrict__ raw, int* __restrict__ flag) {
    if (blockIdx.x == 0 && threadIdx.x == 0) {
        int is64 = 1;
        for (int i = 1; i < 512; i += 2)
            if (raw[i] != 0u) { is64 = 0; break; }
        *flag = is64;
    }
}

// ---------------- h = x @ W  (W staged in LDS, 1 row / thread) --------------
__global__ __launch_bounds__(256) void k_gemm(const float* __restrict__ x,
                                              const float* __restrict__ W,
                                              float* __restrict__ h) {
    __shared__ float Ws[64 * 64];
    const int tid = threadIdx.x;
    #pragma unroll
    for (int i = 0; i < 4; ++i) {
        const int off = tid * 4 + i * 1024;
        *reinterpret_cast<float4*>(&Ws[off]) =
            *reinterpret_cast<const float4*>(&W[off]);
    }
    __syncthreads();
    const int row = blockIdx.x * 256 + tid;
    if (row >= N) return;
    const float* xr = x + (size_t)row * 64;
    float4 acc[16];
    #pragma unroll
    for (int i = 0; i < 16; ++i) acc[i] = make_float4(0.f, 0.f, 0.f, 0.f);
    for (int k = 0; k < 64; k += 4) {
        const float4 xv = *reinterpret_cast<const float4*>(xr + k);
        const float xs[4] = {xv.x, xv.y, xv.z, xv.w};
        #pragma unroll
        for (int kk = 0; kk < 4; ++kk) {
            const float s = xs[kk];
            const float4* wr = reinterpret_cast<const float4*>(&Ws[(k + kk) * 64]);
            #pragma unroll
            for (int d4 = 0; d4 < 16; ++d4) {
                const float4 w = wr[d4];
                acc[d4].x += s * w.x; acc[d4].y += s * w.y;
                acc[d4].z += s * w.z; acc[d4].w += s * w.w;
            }
        }
    }
    float4* hr = reinterpret_cast<float4*>(h + (size_t)row * 64);
    #pragma unroll
    for (int d4 = 0; d4 < 16; ++d4) hr[d4] = acc[d4];
}

// ---------------- degree: init (self-loop = 1), accumulate, rsqrt -----------
__global__ __launch_bounds__(256) void k_deg_init(float* __restrict__ deg,
                                                  double* __restrict__ sums) {
    const int i = blockIdx.x * 256 + threadIdx.x;
    if (i < N) deg[i] = 1.0f;
    if (blockIdx.x == 0 && threadIdx.x < 128) sums[threadIdx.x] = 0.0;
}

__global__ __launch_bounds__(256) void k_deg_accum(const uint32_t* __restrict__ raw,
                                                   const int* __restrict__ flag,
                                                   float* __restrict__ deg) {
    const bool is64 = (*flag != 0);
    for (int e = blockIdx.x * blockDim.x + threadIdx.x; e < E;
         e += gridDim.x * blockDim.x) {
        const int d = (int)(is64 ? raw[2u * (uint32_t)(E + e)] : raw[(uint32_t)(E + e)]);
        atomicAdd(&deg[d], 1.0f);
    }
}

__global__ __launch_bounds__(256) void k_dinv(float* __restrict__ deg) {
    const int i = blockIdx.x * 256 + threadIdx.x;
    if (i < N) deg[i] = rsqrtf(deg[i]);
}

// ---------------- out = h*dinv^2 + b (self-loop + bias init) ---------------
__global__ __launch_bounds__(256) void k_agg_init(const float* __restrict__ h,
                                                  const float* __restrict__ dinv,
                                                  const float* __restrict__ b,
                                                  float* __restrict__ out) {
    const int idx = blockIdx.x * 256 + threadIdx.x;     // grid covers exactly N*D
    const float di = dinv[idx >> 6];
    out[idx] = h[idx] * di * di + b[idx & 63];
}

// ---------------- edge scatter: out[dst] += h[src] * dinv_s*dinv_d ---------
__global__ __launch_bounds__(256) void k_scatter(const float* __restrict__ h,
                                                 const float* __restrict__ dinv,
                                                 const uint32_t* __restrict__ raw,
                                                 const int* __restrict__ flag,
                                                 float* __restrict__ out) {
    const bool is64 = (*flag != 0);
    const int lane = threadIdx.x & 63;
    const int egrp = threadIdx.x >> 6;                  // 4 edges per block
    for (int e = blockIdx.x * 4 + egrp; e < E; e += gridDim.x * 4) {
        const int s = (int)(is64 ? raw[2u * (uint32_t)e] : raw[(uint32_t)e]);
        const int d = (int)(is64 ? raw[2u * (uint32_t)(E + e)] : raw[(uint32_t)(E + e)]);
        const float nrm = dinv[s] * dinv[d];
        const float v = h[(size_t)s * 64 + lane] * nrm;
        atomicAdd(&out[(size_t)d * 64 + lane], v);
    }
}

// ---------------- BN batch stats: per-column sum & sumsq -------------------
__global__ __launch_bounds__(256) void k_bn_stats(const float* __restrict__ out,
                                                  double* __restrict__ sums) {
    const int tid = threadIdx.x;
    const int c = tid & 63;
    const int rg = tid >> 6;                            // 4 rows per block pass
    float s = 0.f, sq = 0.f;
    for (int r = blockIdx.x * 4 + rg; r < N; r += gridDim.x * 4) {
        const float v = out[(size_t)r * 64 + c];
        s += v; sq += v * v;
    }
    __shared__ float ls[256], lq[256];
    ls[tid] = s; lq[tid] = sq;
    __syncthreads();
    if (tid < 64) {
        s  = ls[tid] + ls[tid + 64] + ls[tid + 128] + ls[tid + 192];
        sq = lq[tid] + lq[tid + 64] + lq[tid + 128] + lq[tid + 192];
        atomicAdd(&sums[tid], (double)s);
        atomicAdd(&sums[64 + tid], (double)sq);
    }
}

__global__ __launch_bounds__(64) void k_bn_fin(const double* __restrict__ sums,
                                               const float* __restrict__ gamma,
                                               const float* __restrict__ beta,
                                               float* __restrict__ scale,
                                               float* __restrict__ shift) {
    const int c = threadIdx.x;
    const double mean = sums[c] / (double)N;
    const double var  = sums[64 + c] / (double)N - mean * mean;
    const float rstd  = (float)(1.0 / sqrt(var + (double)EPS));
    const float sc = gamma[c] * rstd;
    scale[c] = sc;
    shift[c] = beta[c] - (float)mean * sc;
}

// -------- fused BN-apply + dropout (partitionable threefry) + ReLU ---------
// Partitionable mode, bit_width=32 path (jax/_src/prng.py):
//   bits1, bits2 = threefry2x32(key, (counts>>32, counts&0xffffffff))
//   return convert_element_type(bits1 ^ bits2, uint32)      <-- XOR fold
__global__ __launch_bounds__(256) void k_bn_drop_relu(float* __restrict__ out,
                                                      const float* __restrict__ scale,
                                                      const float* __restrict__ shift) {
    const int j = blockIdx.x * 256 + threadIdx.x;       // grid covers exactly N*D
    uint32_t x0 = 0u, x1 = (uint32_t)j;                 // counter = (0, i), i < 2^32
    threefry2x32_k42(x0, x1);
    const uint32_t bits = x0 ^ x1;                      // XOR fold of both words
    const int c = j & 63;
    float v = out[j] * scale[c] + shift[c];
    const float u = __uint_as_float((bits >> 9) | 0x3F800000u) - 1.0f;
    v = (u < 0.9f) ? v * (1.0f / 0.9f) : 0.0f;
    out[j] = fmaxf(v, 0.f);
}

// ---------------------------------------------------------------------------
extern "C" void kernel_launch(void* const* d_in, const int* in_sizes, int n_in,
                              void* d_out, int out_size, void* d_ws, size_t ws_size,
                              hipStream_t stream) {
    const float*    x     = (const float*)d_in[0];
    const uint32_t* ei    = (const uint32_t*)d_in[1];   // int32 OR int64 — detected
    const float*    W     = (const float*)d_in[2];
    const float*    b     = (const float*)d_in[3];
    const float*    gamma = (const float*)d_in[4];
    const float*    beta  = (const float*)d_in[5];
    float* out = (float*)d_out;

    float*  h    = (float*)d_ws;                        // N*D floats
    float*  deg  = h + (size_t)N * D;                   // N floats (becomes dinv)
    double* sums = (double*)(deg + N);                  // 128 doubles (8-aligned)
    float*  scale = (float*)(sums + 128);
    float*  shift = scale + 64;
    int*    flag  = (int*)(shift + 64);

    const int nb_rows = (N + 255) / 256;                // 391

    k_detect<<<1, 64, 0, stream>>>(ei, flag);
    k_gemm<<<nb_rows, 256, 0, stream>>>(x, W, h);
    k_deg_init<<<nb_rows, 256, 0, stream>>>(deg, sums);
    k_deg_accum<<<2048, 256, 0, stream>>>(ei, flag, deg);
    k_dinv<<<nb_rows, 256, 0, stream>>>(deg);
    k_agg_init<<<(N * D) / 256, 256, 0, stream>>>(h, deg, b, out);
    k_scatter<<<2048, 256, 0, stream>>>(h, deg, ei, flag, out);
    k_bn_stats<<<1024, 256, 0, stream>>>(out, sums);
    k_bn_fin<<<1, 64, 0, stream>>>(sums, gamma, beta, scale, shift);
    k_bn_drop_relu<<<(N * D) / 256, 256, 0, stream>>>(out, scale, shift);
}

// Round 6
// 414.284 us; speedup vs baseline: 1.2625x; 1.2625x over previous
//
#include <hip/hip_runtime.h>
#include <cstdint>

static constexpr int N = 100000;
static constexpr int D = 64;
static constexpr int E = 1250000;
static constexpr int NB = (N + 1023) / 1024;   // 98 scan blocks
static constexpr float EPS = 1e-5f;

// ---------------- threefry2x32, 20 rounds, key = (0, 42) --------------------
__device__ __forceinline__ uint32_t rotl32(uint32_t x, int r) {
    return (x << r) | (x >> (32 - r));
}

__device__ __forceinline__ void threefry2x32_k42(uint32_t& x0, uint32_t& x1) {
    const uint32_t ks0 = 0u, ks1 = 42u, ks2 = 0x1BD11BDAu ^ 0u ^ 42u;
    x0 += ks0; x1 += ks1;
#define TF_R4(a,b,c,d) \
    x0 += x1; x1 = rotl32(x1,a); x1 ^= x0; \
    x0 += x1; x1 = rotl32(x1,b); x1 ^= x0; \
    x0 += x1; x1 = rotl32(x1,c); x1 ^= x0; \
    x0 += x1; x1 = rotl32(x1,d); x1 ^= x0;
    TF_R4(13,15,26,6);  x0 += ks1; x1 += ks2 + 1u;
    TF_R4(17,29,16,24); x0 += ks2; x1 += ks0 + 2u;
    TF_R4(13,15,26,6);  x0 += ks0; x1 += ks1 + 3u;
    TF_R4(17,29,16,24); x0 += ks1; x1 += ks2 + 4u;
    TF_R4(13,15,26,6);  x0 += ks2; x1 += ks0 + 5u;
#undef TF_R4
}

// ---------------- edge_index dtype detection (int64 vs int32) ---------------
__global__ void k_detect(const uint32_t* __restrict__ raw, int* __restrict__ flag) {
    if (blockIdx.x == 0 && threadIdx.x == 0) {
        int is64 = 1;
        for (int i = 1; i < 512; i += 2)
            if (raw[i] != 0u) { is64 = 0; break; }
        *flag = is64;
    }
}

__device__ __forceinline__ int load_idx(const uint32_t* raw, bool is64, int i) {
    return (int)(is64 ? raw[2u * (uint32_t)i] : raw[(uint32_t)i]);
}

// ---------------- h = x @ W  (W staged in LDS, 1 row / thread) --------------
__global__ __launch_bounds__(256) void k_gemm(const float* __restrict__ x,
                                              const float* __restrict__ W,
                                              float* __restrict__ h) {
    __shared__ float Ws[64 * 64];
    const int tid = threadIdx.x;
    #pragma unroll
    for (int i = 0; i < 4; ++i) {
        const int off = tid * 4 + i * 1024;
        *reinterpret_cast<float4*>(&Ws[off]) =
            *reinterpret_cast<const float4*>(&W[off]);
    }
    __syncthreads();
    const int row = blockIdx.x * 256 + tid;
    if (row >= N) return;
    const float* xr = x + (size_t)row * 64;
    float4 acc[16];
    #pragma unroll
    for (int i = 0; i < 16; ++i) acc[i] = make_float4(0.f, 0.f, 0.f, 0.f);
    for (int k = 0; k < 64; k += 4) {
        const float4 xv = *reinterpret_cast<const float4*>(xr + k);
        const float xs[4] = {xv.x, xv.y, xv.z, xv.w};
        #pragma unroll
        for (int kk = 0; kk < 4; ++kk) {
            const float s = xs[kk];
            const float4* wr = reinterpret_cast<const float4*>(&Ws[(k + kk) * 64]);
            #pragma unroll
            for (int d4 = 0; d4 < 16; ++d4) {
                const float4 w = wr[d4];
                acc[d4].x += s * w.x; acc[d4].y += s * w.y;
                acc[d4].z += s * w.z; acc[d4].w += s * w.w;
            }
        }
    }
    float4* hr = reinterpret_cast<float4*>(h + (size_t)row * 64);
    #pragma unroll
    for (int d4 = 0; d4 < 16; ++d4) hr[d4] = acc[d4];
}

// ---------------- zero counters + BN sums ----------------------------------
__global__ __launch_bounds__(256) void k_zero(uint32_t* __restrict__ cnt,
                                              double* __restrict__ sums) {
    const int i = blockIdx.x * 256 + threadIdx.x;
    if (i < N) cnt[i] = 0u;
    if (blockIdx.x == 0 && threadIdx.x < 128) sums[threadIdx.x] = 0.0;
}

// ---------------- in-degree histogram --------------------------------------
__global__ __launch_bounds__(256) void k_hist(const uint32_t* __restrict__ raw,
                                              const int* __restrict__ flag,
                                              uint32_t* __restrict__ cnt) {
    const bool is64 = (*flag != 0);
    for (int e = blockIdx.x * blockDim.x + threadIdx.x; e < E;
         e += gridDim.x * blockDim.x)
        atomicAdd(&cnt[load_idx(raw, is64, E + e)], 1u);
}

// ---------------- dinv = rsqrt(in-deg + 1)  (self-loop) --------------------
__global__ __launch_bounds__(256) void k_dinv(const uint32_t* __restrict__ cnt,
                                              float* __restrict__ dinv) {
    const int i = blockIdx.x * 256 + threadIdx.x;
    if (i < N) dinv[i] = rsqrtf((float)(cnt[i] + 1u));
}

// ---------------- 3-kernel exclusive scan over cnt → rowptr ----------------
__global__ __launch_bounds__(1024) void k_scanA(const uint32_t* __restrict__ cnt,
                                                uint32_t* __restrict__ partial) {
    __shared__ uint32_t ls[1024];
    const int t = threadIdx.x;
    const int i = blockIdx.x * 1024 + t;
    ls[t] = (i < N) ? cnt[i] : 0u;
    __syncthreads();
    for (int off = 512; off > 0; off >>= 1) {
        if (t < off) ls[t] += ls[t + off];
        __syncthreads();
    }
    if (t == 0) partial[blockIdx.x] = ls[0];
}

__global__ void k_scanB(uint32_t* __restrict__ partial, uint32_t* __restrict__ rowptr) {
    if (blockIdx.x == 0 && threadIdx.x == 0) {
        uint32_t run = 0;
        for (int b = 0; b < NB; ++b) { uint32_t t = partial[b]; partial[b] = run; run += t; }
        rowptr[N] = run;                        // == E
    }
}

__global__ __launch_bounds__(1024) void k_scanC(const uint32_t* __restrict__ partial,
                                                uint32_t* __restrict__ cnt,   // becomes cursor
                                                uint32_t* __restrict__ rowptr) {
    __shared__ uint32_t ls[1024];
    const int t = threadIdx.x;
    const int i = blockIdx.x * 1024 + t;
    const uint32_t x = (i < N) ? cnt[i] : 0u;
    ls[t] = x;
    __syncthreads();
    for (int off = 1; off < 1024; off <<= 1) {
        const uint32_t v = (t >= off) ? ls[t - off] : 0u;
        __syncthreads();
        ls[t] += v;
        __syncthreads();
    }
    if (i < N) {
        const uint32_t r = partial[blockIdx.x] + ls[t] - x;  // exclusive
        rowptr[i] = r;
        cnt[i] = r;                                          // cursor copy
    }
}

// ---------------- fill CSR src list ----------------------------------------
__global__ __launch_bounds__(256) void k_fill(const uint32_t* __restrict__ raw,
                                              const int* __restrict__ flag,
                                              uint32_t* __restrict__ cursor,
                                              uint32_t* __restrict__ csr) {
    const bool is64 = (*flag != 0);
    for (int e = blockIdx.x * blockDim.x + threadIdx.x; e < E;
         e += gridDim.x * blockDim.x) {
        const int s = load_idx(raw, is64, e);
        const int d = load_idx(raw, is64, E + e);
        const uint32_t pos = atomicAdd(&cursor[d], 1u);
        csr[pos] = (uint32_t)s;
    }
}

// -------- gather-side aggregate: out[d] = Σ h[s]·dinv[s]·dinv[d] + self + b --
__global__ __launch_bounds__(256) void k_gather(const float* __restrict__ h,
                                                const float* __restrict__ dinv,
                                                const uint32_t* __restrict__ rowptr,
                                                const uint32_t* __restrict__ csr,
                                                const float* __restrict__ b,
                                                float* __restrict__ out) {
    const int lane = threadIdx.x & 63;
    const int d = blockIdx.x * 4 + (threadIdx.x >> 6);   // 25000×4 waves == N
    const uint32_t beg = rowptr[d], end = rowptr[d + 1];
    const float dd = dinv[d];
    float acc = h[(size_t)d * 64 + lane] * dd * dd + b[lane];
    for (uint32_t base = beg; base < end; base += 64) {
        const int m = (int)min(64u, end - base);
        int   s_l = 0; float n_l = 0.f;
        if (base + lane < end) {
            s_l = (int)csr[base + lane];                 // coalesced
            n_l = dinv[s_l];
        }
        for (int j = 0; j < m; ++j) {
            const int   s  = __shfl(s_l, j);
            const float nr = __shfl(n_l, j) * dd;
            acc += h[(size_t)s * 64 + lane] * nr;        // 256B coalesced per wave
        }
    }
    out[(size_t)d * 64 + lane] = acc;
}

// ---------------- BN batch stats: per-column sum & sumsq -------------------
__global__ __launch_bounds__(256) void k_bn_stats(const float* __restrict__ out,
                                                  double* __restrict__ sums) {
    const int tid = threadIdx.x;
    const int c = tid & 63;
    const int rg = tid >> 6;
    float s = 0.f, sq = 0.f;
    for (int r = blockIdx.x * 4 + rg; r < N; r += gridDim.x * 4) {
        const float v = out[(size_t)r * 64 + c];
        s += v; sq += v * v;
    }
    __shared__ float ls[256], lq[256];
    ls[tid] = s; lq[tid] = sq;
    __syncthreads();
    if (tid < 64) {
        s  = ls[tid] + ls[tid + 64] + ls[tid + 128] + ls[tid + 192];
        sq = lq[tid] + lq[tid + 64] + lq[tid + 128] + lq[tid + 192];
        atomicAdd(&sums[tid], (double)s);
        atomicAdd(&sums[64 + tid], (double)sq);
    }
}

__global__ __launch_bounds__(64) void k_bn_fin(const double* __restrict__ sums,
                                               const float* __restrict__ gamma,
                                               const float* __restrict__ beta,
                                               float* __restrict__ scale,
                                               float* __restrict__ shift) {
    const int c = threadIdx.x;
    const double mean = sums[c] / (double)N;
    const double var  = sums[64 + c] / (double)N - mean * mean;
    const float rstd  = (float)(1.0 / sqrt(var + (double)EPS));
    const float sc = gamma[c] * rstd;
    scale[c] = sc;
    shift[c] = beta[c] - (float)mean * sc;
}

// -------- fused BN-apply + dropout (partitionable threefry, XOR fold) + ReLU
__global__ __launch_bounds__(256) void k_bn_drop_relu(float* __restrict__ out,
                                                      const float* __restrict__ scale,
                                                      const float* __restrict__ shift) {
    const int j = blockIdx.x * 256 + threadIdx.x;
    uint32_t x0 = 0u, x1 = (uint32_t)j;
    threefry2x32_k42(x0, x1);
    const uint32_t bits = x0 ^ x1;
    const int c = j & 63;
    float v = out[j] * scale[c] + shift[c];
    const float u = __uint_as_float((bits >> 9) | 0x3F800000u) - 1.0f;
    v = (u < 0.9f) ? v * (1.0f / 0.9f) : 0.0f;
    out[j] = fmaxf(v, 0.f);
}

// ---------------------------------------------------------------------------
extern "C" void kernel_launch(void* const* d_in, const int* in_sizes, int n_in,
                              void* d_out, int out_size, void* d_ws, size_t ws_size,
                              hipStream_t stream) {
    const float*    x     = (const float*)d_in[0];
    const uint32_t* ei    = (const uint32_t*)d_in[1];
    const float*    W     = (const float*)d_in[2];
    const float*    b     = (const float*)d_in[3];
    const float*    gamma = (const float*)d_in[4];
    const float*    beta  = (const float*)d_in[5];
    float* out = (float*)d_out;

    float*    h      = (float*)d_ws;                 // N*D f32
    float*    dinv   = h + (size_t)N * D;            // N f32
    double*   sums   = (double*)(dinv + N);          // 128 f64 (byte 26,000,000 — 8-aligned)
    float*    scale  = (float*)(sums + 128);         // 64
    float*    shift  = scale + 64;                   // 64
    int*      flag   = (int*)(shift + 64);           // 1
    uint32_t* partial = (uint32_t*)(flag + 1);       // 128
    uint32_t* cnt    = partial + 128;                // N (histogram → cursor)
    uint32_t* rowptr = cnt + N;                      // N+1
    uint32_t* csr    = rowptr + N + 1;               // E   (total ≈ 31.8 MB)

    const int nb256 = (N + 255) / 256;               // 391

    k_detect<<<1, 64, 0, stream>>>(ei, flag);
    k_gemm<<<nb256, 256, 0, stream>>>(x, W, h);
    k_zero<<<nb256, 256, 0, stream>>>(cnt, sums);
    k_hist<<<2048, 256, 0, stream>>>(ei, flag, cnt);
    k_dinv<<<nb256, 256, 0, stream>>>(cnt, dinv);
    k_scanA<<<NB, 1024, 0, stream>>>(cnt, partial);
    k_scanB<<<1, 1, 0, stream>>>(partial, rowptr);
    k_scanC<<<NB, 1024, 0, stream>>>(partial, cnt, rowptr);
    k_fill<<<2048, 256, 0, stream>>>(ei, flag, cnt, csr);
    k_gather<<<N / 4, 256, 0, stream>>>(h, dinv, rowptr, csr, b, out);
    k_bn_stats<<<1024, 256, 0, stream>>>(out, sums);
    k_bn_fin<<<1, 64, 0, stream>>>(sums, gamma, beta, scale, shift);
    k_bn_drop_relu<<<(N * D) / 256, 256, 0, stream>>>(out, scale, shift);
}

// Round 7
// 359.647 us; speedup vs baseline: 1.4543x; 1.1519x over previous
//
#include <hip/hip_runtime.h>
#include <cstdint>

static constexpr int N = 100000;
static constexpr int D = 64;
static constexpr int E = 1250000;
static constexpr int NB = (N + 1023) / 1024;   // 98 scan blocks
static constexpr int BS = 12500;               // dst bucket size (N/8)
static constexpr int FILL_CHUNKS = 256;
static constexpr int ECH = (E + FILL_CHUNKS - 1) / FILL_CHUNKS;  // 4883
static constexpr float EPS = 1e-5f;

// ---------------- threefry2x32, 20 rounds, key = (0, 42) --------------------
__device__ __forceinline__ uint32_t rotl32(uint32_t x, int r) {
    return (x << r) | (x >> (32 - r));
}

__device__ __forceinline__ void threefry2x32_k42(uint32_t& x0, uint32_t& x1) {
    const uint32_t ks0 = 0u, ks1 = 42u, ks2 = 0x1BD11BDAu ^ 0u ^ 42u;
    x0 += ks0; x1 += ks1;
#define TF_R4(a,b,c,d) \
    x0 += x1; x1 = rotl32(x1,a); x1 ^= x0; \
    x0 += x1; x1 = rotl32(x1,b); x1 ^= x0; \
    x0 += x1; x1 = rotl32(x1,c); x1 ^= x0; \
    x0 += x1; x1 = rotl32(x1,d); x1 ^= x0;
    TF_R4(13,15,26,6);  x0 += ks1; x1 += ks2 + 1u;
    TF_R4(17,29,16,24); x0 += ks2; x1 += ks0 + 2u;
    TF_R4(13,15,26,6);  x0 += ks0; x1 += ks1 + 3u;
    TF_R4(17,29,16,24); x0 += ks1; x1 += ks2 + 4u;
    TF_R4(13,15,26,6);  x0 += ks2; x1 += ks0 + 5u;
#undef TF_R4
}

// ---------------- bf16 helpers ---------------------------------------------
__device__ __forceinline__ uint32_t f2bf(float f) {          // RNE
    const uint32_t u = __float_as_uint(f);
    return (u + 0x7FFFu + ((u >> 16) & 1u)) >> 16;
}
__device__ __forceinline__ float bf2f(uint32_t u) {
    return __uint_as_float(u << 16);
}

// ---------------- edge_index dtype detection (int64 vs int32) ---------------
__global__ void k_detect(const uint32_t* __restrict__ raw, int* __restrict__ flag) {
    if (blockIdx.x == 0 && threadIdx.x == 0) {
        int is64 = 1;
        for (int i = 1; i < 512; i += 2)
            if (raw[i] != 0u) { is64 = 0; break; }
        *flag = is64;
    }
}

__device__ __forceinline__ int load_idx(const uint32_t* raw, bool is64, int i) {
    return (int)(is64 ? raw[2u * (uint32_t)i] : raw[(uint32_t)i]);
}

// ---------------- zero counters + BN sums ----------------------------------
__global__ __launch_bounds__(256) void k_zero(uint32_t* __restrict__ cnt,
                                              double* __restrict__ sums) {
    const int i = blockIdx.x * 256 + threadIdx.x;
    if (i < N) cnt[i] = 0u;
    if (blockIdx.x == 0 && threadIdx.x < 128) sums[threadIdx.x] = 0.0;
}

// ---------------- in-degree histogram --------------------------------------
__global__ __launch_bounds__(256) void k_hist(const uint32_t* __restrict__ raw,
                                              const int* __restrict__ flag,
                                              uint32_t* __restrict__ cnt) {
    const bool is64 = (*flag != 0);
    for (int e = blockIdx.x * blockDim.x + threadIdx.x; e < E;
         e += gridDim.x * blockDim.x)
        atomicAdd(&cnt[load_idx(raw, is64, E + e)], 1u);
}

// ---------------- dinv = rsqrt(in-deg + 1)  (self-loop) --------------------
__global__ __launch_bounds__(256) void k_dinv(const uint32_t* __restrict__ cnt,
                                              float* __restrict__ dinv) {
    const int i = blockIdx.x * 256 + threadIdx.x;
    if (i < N) dinv[i] = rsqrtf((float)(cnt[i] + 1u));
}

// ------- hs = bf16( (x @ W) * dinv[row] )  — dinv folded into GEMM ---------
__global__ __launch_bounds__(256) void k_gemm(const float* __restrict__ x,
                                              const float* __restrict__ W,
                                              const float* __restrict__ dinv,
                                              uint32_t* __restrict__ hs) {  // packed 2×bf16
    __shared__ float Ws[64 * 64];
    const int tid = threadIdx.x;
    #pragma unroll
    for (int i = 0; i < 4; ++i) {
        const int off = tid * 4 + i * 1024;
        *reinterpret_cast<float4*>(&Ws[off]) =
            *reinterpret_cast<const float4*>(&W[off]);
    }
    __syncthreads();
    const int row = blockIdx.x * 256 + tid;
    if (row >= N) return;
    const float* xr = x + (size_t)row * 64;
    float4 acc[16];
    #pragma unroll
    for (int i = 0; i < 16; ++i) acc[i] = make_float4(0.f, 0.f, 0.f, 0.f);
    for (int k = 0; k < 64; k += 4) {
        const float4 xv = *reinterpret_cast<const float4*>(xr + k);
        const float xs[4] = {xv.x, xv.y, xv.z, xv.w};
        #pragma unroll
        for (int kk = 0; kk < 4; ++kk) {
            const float s = xs[kk];
            const float4* wr = reinterpret_cast<const float4*>(&Ws[(k + kk) * 64]);
            #pragma unroll
            for (int d4 = 0; d4 < 16; ++d4) {
                const float4 w = wr[d4];
                acc[d4].x += s * w.x; acc[d4].y += s * w.y;
                acc[d4].z += s * w.z; acc[d4].w += s * w.w;
            }
        }
    }
    const float sc = dinv[row];
    uint32_t pack[32];
    #pragma unroll
    for (int i = 0; i < 16; ++i) {
        pack[2 * i]     = f2bf(acc[i].x * sc) | (f2bf(acc[i].y * sc) << 16);
        pack[2 * i + 1] = f2bf(acc[i].z * sc) | (f2bf(acc[i].w * sc) << 16);
    }
    uint4* hr = reinterpret_cast<uint4*>(hs + (size_t)row * 32);
    #pragma unroll
    for (int i = 0; i < 8; ++i) hr[i] = reinterpret_cast<const uint4*>(pack)[i];
}

// ---------------- 3-kernel exclusive scan over cnt → rowptr ----------------
__global__ __launch_bounds__(1024) void k_scanA(const uint32_t* __restrict__ cnt,
                                                uint32_t* __restrict__ partial) {
    __shared__ uint32_t ls[1024];
    const int t = threadIdx.x;
    const int i = blockIdx.x * 1024 + t;
    ls[t] = (i < N) ? cnt[i] : 0u;
    __syncthreads();
    for (int off = 512; off > 0; off >>= 1) {
        if (t < off) ls[t] += ls[t + off];
        __syncthreads();
    }
    if (t == 0) partial[blockIdx.x] = ls[0];
}

__global__ void k_scanB(uint32_t* __restrict__ partial, uint32_t* __restrict__ rowptr) {
    if (blockIdx.x == 0 && threadIdx.x == 0) {
        uint32_t run = 0;
        for (int b = 0; b < NB; ++b) { uint32_t t = partial[b]; partial[b] = run; run += t; }
        rowptr[N] = run;                        // == E
    }
}

__global__ __launch_bounds__(1024) void k_scanC(const uint32_t* __restrict__ partial,
                                                uint32_t* __restrict__ cnt,   // becomes cursor
                                                uint32_t* __restrict__ rowptr) {
    __shared__ uint32_t ls[1024];
    const int t = threadIdx.x;
    const int i = blockIdx.x * 1024 + t;
    const uint32_t x = (i < N) ? cnt[i] : 0u;
    ls[t] = x;
    __syncthreads();
    for (int off = 1; off < 1024; off <<= 1) {
        const uint32_t v = (t >= off) ? ls[t - off] : 0u;
        __syncthreads();
        ls[t] += v;
        __syncthreads();
    }
    if (i < N) {
        const uint32_t r = partial[blockIdx.x] + ls[t] - x;  // exclusive
        rowptr[i] = r;
        cnt[i] = r;                                          // cursor copy
    }
}

// ------- XCD-bucketed CSR fill: block b → dst bucket (b&7), chunk (b>>3) ----
// All csr/cursor writes of one bucket stay in one XCD's L2 (blockIdx%8 → XCD
// round-robin heuristic) → lines coalesce, no partial-line write-through.
__global__ __launch_bounds__(256) void k_fill(const uint32_t* __restrict__ raw,
                                              const int* __restrict__ flag,
                                              uint32_t* __restrict__ cursor,
                                              uint32_t* __restrict__ csr) {
    const bool is64 = (*flag != 0);
    const int bucket = blockIdx.x & 7;
    const int chunk  = blockIdx.x >> 3;
    const int lo = bucket * BS, hi = lo + BS;
    const int e0 = chunk * ECH;
    const int e1 = min(E, e0 + ECH);
    for (int e = e0 + (int)threadIdx.x; e < e1; e += 256) {
        const int dx = load_idx(raw, is64, E + e);
        if (dx >= lo && dx < hi) {
            const int s = load_idx(raw, is64, e);
            const uint32_t pos = atomicAdd(&cursor[dx], 1u);
            csr[pos] = (uint32_t)s;
        }
    }
}

// ---- gather: out[d] = (Σ_src hs[src] + hs[d]) · dinv[d] + b  (no atomics) --
__global__ __launch_bounds__(256) void k_gather(const ushort* __restrict__ hs,
                                                const float* __restrict__ dinv,
                                                const uint32_t* __restrict__ rowptr,
                                                const uint32_t* __restrict__ csr,
                                                const float* __restrict__ b,
                                                float* __restrict__ out) {
    const int lane = threadIdx.x & 63;
    const int d = blockIdx.x * 4 + (threadIdx.x >> 6);   // 25000×4 waves == N
    const uint32_t beg = rowptr[d], end = rowptr[d + 1];
    float acc = bf2f(hs[(size_t)d * 64 + lane]);         // self-loop term
    for (uint32_t base = beg; base < end; base += 64) {
        const int m = (int)min(64u, end - base);
        int s_l = 0;
        if (base + lane < end) s_l = (int)csr[base + lane];   // coalesced
        for (int j = 0; j < m; ++j) {
            const int s = __shfl(s_l, j);
            acc += bf2f(hs[(size_t)s * 64 + lane]);      // 128B coalesced per wave
        }
    }
    out[(size_t)d * 64 + lane] = acc * dinv[d] + b[lane];
}

// ---------------- BN batch stats: per-column sum & sumsq -------------------
__global__ __launch_bounds__(256) void k_bn_stats(const float* __restrict__ out,
                                                  double* __restrict__ sums) {
    const int tid = threadIdx.x;
    const int c = tid & 63;
    const int rg = tid >> 6;
    float s = 0.f, sq = 0.f;
    for (int r = blockIdx.x * 4 + rg; r < N; r += gridDim.x * 4) {
        const float v = out[(size_t)r * 64 + c];
        s += v; sq += v * v;
    }
    __shared__ float ls[256], lq[256];
    ls[tid] = s; lq[tid] = sq;
    __syncthreads();
    if (tid < 64) {
        s  = ls[tid] + ls[tid + 64] + ls[tid + 128] + ls[tid + 192];
        sq = lq[tid] + lq[tid + 64] + lq[tid + 128] + lq[tid + 192];
        atomicAdd(&sums[tid], (double)s);
        atomicAdd(&sums[64 + tid], (double)sq);
    }
}

__global__ __launch_bounds__(64) void k_bn_fin(const double* __restrict__ sums,
                                               const float* __restrict__ gamma,
                                               const float* __restrict__ beta,
                                               float* __restrict__ scale,
                                               float* __restrict__ shift) {
    const int c = threadIdx.x;
    const double mean = sums[c] / (double)N;
    const double var  = sums[64 + c] / (double)N - mean * mean;
    const float rstd  = (float)(1.0 / sqrt(var + (double)EPS));
    const float sc = gamma[c] * rstd;
    scale[c] = sc;
    shift[c] = beta[c] - (float)mean * sc;
}

// -------- fused BN-apply + dropout (partitionable threefry, XOR fold) + ReLU
__global__ __launch_bounds__(256) void k_bn_drop_relu(float* __restrict__ out,
                                                      const float* __restrict__ scale,
                                                      const float* __restrict__ shift) {
    const int j = blockIdx.x * 256 + threadIdx.x;
    uint32_t x0 = 0u, x1 = (uint32_t)j;
    threefry2x32_k42(x0, x1);
    const uint32_t bits = x0 ^ x1;
    const int c = j & 63;
    float v = out[j] * scale[c] + shift[c];
    const float u = __uint_as_float((bits >> 9) | 0x3F800000u) - 1.0f;
    v = (u < 0.9f) ? v * (1.0f / 0.9f) : 0.0f;
    out[j] = fmaxf(v, 0.f);
}

// ---------------------------------------------------------------------------
extern "C" void kernel_launch(void* const* d_in, const int* in_sizes, int n_in,
                              void* d_out, int out_size, void* d_ws, size_t ws_size,
                              hipStream_t stream) {
    const float*    x     = (const float*)d_in[0];
    const uint32_t* ei    = (const uint32_t*)d_in[1];
    const float*    W     = (const float*)d_in[2];
    const float*    b     = (const float*)d_in[3];
    const float*    gamma = (const float*)d_in[4];
    const float*    beta  = (const float*)d_in[5];
    float* out = (float*)d_out;

    uint32_t* hs     = (uint32_t*)d_ws;              // N*32 u32 (N×64 bf16, 12.8 MB)
    float*    dinv   = (float*)(hs + (size_t)N * 32);// N f32
    double*   sums   = (double*)(dinv + N);          // 128 f64 (byte 13,200,000 — 8-aligned)
    float*    scale  = (float*)(sums + 128);         // 64
    float*    shift  = scale + 64;                   // 64
    int*      flag   = (int*)(shift + 64);           // 1
    uint32_t* partial = (uint32_t*)(flag + 1);       // 128
    uint32_t* cnt    = partial + 128;                // N (histogram → cursor)
    uint32_t* rowptr = cnt + N;                      // N+1
    uint32_t* csr    = rowptr + N + 1;               // E   (total ≈ 19 MB)

    const int nb256 = (N + 255) / 256;               // 391

    k_detect<<<1, 64, 0, stream>>>(ei, flag);
    k_zero<<<nb256, 256, 0, stream>>>(cnt, sums);
    k_hist<<<2048, 256, 0, stream>>>(ei, flag, cnt);
    k_dinv<<<nb256, 256, 0, stream>>>(cnt, dinv);
    k_gemm<<<nb256, 256, 0, stream>>>(x, W, dinv, hs);
    k_scanA<<<NB, 1024, 0, stream>>>(cnt, partial);
    k_scanB<<<1, 1, 0, stream>>>(partial, rowptr);
    k_scanC<<<NB, 1024, 0, stream>>>(partial, cnt, rowptr);
    k_fill<<<8 * FILL_CHUNKS, 256, 0, stream>>>(ei, flag, cnt, csr);
    k_gather<<<N / 4, 256, 0, stream>>>((const ushort*)hs, dinv, rowptr, csr, b, out);
    k_bn_stats<<<1024, 256, 0, stream>>>(out, sums);
    k_bn_fin<<<1, 64, 0, stream>>>(sums, gamma, beta, scale, shift);
    k_bn_drop_relu<<<(N * D) / 256, 256, 0, stream>>>(out, scale, shift);
}

// Round 8
// 328.833 us; speedup vs baseline: 1.5905x; 1.0937x over previous
//
#include <hip/hip_runtime.h>
#include <cstdint>

static constexpr int N = 100000;
static constexpr int D = 64;
static constexpr int E = 1250000;
static constexpr int NB = (N + 1023) / 1024;   // 98 scan blocks
static constexpr int BS = 12500;               // dst bucket size (N/8)
static constexpr int FILL_CHUNKS = 256;
static constexpr int ECH = (E + FILL_CHUNKS - 1) / FILL_CHUNKS;  // 4883
static constexpr int HIST_CHUNKS = 64;
static constexpr int EHC = (E + HIST_CHUNKS - 1) / HIST_CHUNKS;  // 19532
static constexpr float EPS = 1e-5f;

// ---------------- threefry2x32, 20 rounds, key = (0, 42) --------------------
__device__ __forceinline__ uint32_t rotl32(uint32_t x, int r) {
    return (x << r) | (x >> (32 - r));
}

__device__ __forceinline__ void threefry2x32_k42(uint32_t& x0, uint32_t& x1) {
    const uint32_t ks0 = 0u, ks1 = 42u, ks2 = 0x1BD11BDAu ^ 0u ^ 42u;
    x0 += ks0; x1 += ks1;
#define TF_R4(a,b,c,d) \
    x0 += x1; x1 = rotl32(x1,a); x1 ^= x0; \
    x0 += x1; x1 = rotl32(x1,b); x1 ^= x0; \
    x0 += x1; x1 = rotl32(x1,c); x1 ^= x0; \
    x0 += x1; x1 = rotl32(x1,d); x1 ^= x0;
    TF_R4(13,15,26,6);  x0 += ks1; x1 += ks2 + 1u;
    TF_R4(17,29,16,24); x0 += ks2; x1 += ks0 + 2u;
    TF_R4(13,15,26,6);  x0 += ks0; x1 += ks1 + 3u;
    TF_R4(17,29,16,24); x0 += ks1; x1 += ks2 + 4u;
    TF_R4(13,15,26,6);  x0 += ks2; x1 += ks0 + 5u;
#undef TF_R4
}

// ---------------- bf16 helpers ---------------------------------------------
__device__ __forceinline__ uint32_t f2bf(float f) {          // RNE
    const uint32_t u = __float_as_uint(f);
    return (u + 0x7FFFu + ((u >> 16) & 1u)) >> 16;
}
__device__ __forceinline__ float bfl(uint32_t u) {           // low bf16 of u32
    return __uint_as_float(u << 16);
}
__device__ __forceinline__ float bfh(uint32_t u) {           // high bf16 of u32
    return __uint_as_float(u & 0xFFFF0000u);
}

// ---------------- edge_index dtype detection (int64 vs int32) ---------------
__global__ void k_detect(const uint32_t* __restrict__ raw, int* __restrict__ flag) {
    if (blockIdx.x == 0 && threadIdx.x == 0) {
        int is64 = 1;
        for (int i = 1; i < 512; i += 2)
            if (raw[i] != 0u) { is64 = 0; break; }
        *flag = is64;
    }
}

__device__ __forceinline__ int load_idx(const uint32_t* raw, bool is64, int i) {
    return (int)(is64 ? raw[2u * (uint32_t)i] : raw[(uint32_t)i]);
}

// ---------------- zero counters + BN sums ----------------------------------
__global__ __launch_bounds__(256) void k_zero(uint32_t* __restrict__ cnt,
                                              double* __restrict__ sums) {
    const int i = blockIdx.x * 256 + threadIdx.x;
    if (i < N) cnt[i] = 0u;
    if (blockIdx.x == 0 && threadIdx.x < 128) sums[threadIdx.x] = 0.0;
}

// ------- in-degree histogram, XCD-bucketed (atomics stay in one L2) --------
__global__ __launch_bounds__(256) void k_hist(const uint32_t* __restrict__ raw,
                                              const int* __restrict__ flag,
                                              uint32_t* __restrict__ cnt) {
    const bool is64 = (*flag != 0);
    const int bucket = blockIdx.x & 7;
    const int chunk  = blockIdx.x >> 3;
    const int lo = bucket * BS, hi = lo + BS;
    const int e0 = chunk * EHC;
    const int e1 = min(E, e0 + EHC);
    for (int e = e0 + (int)threadIdx.x; e < e1; e += 256) {
        const int dx = load_idx(raw, is64, E + e);
        if (dx >= lo && dx < hi) atomicAdd(&cnt[dx], 1u);
    }
}

// ---------------- dinv = rsqrt(in-deg + 1)  (self-loop) --------------------
__global__ __launch_bounds__(256) void k_dinv(const uint32_t* __restrict__ cnt,
                                              float* __restrict__ dinv) {
    const int i = blockIdx.x * 256 + threadIdx.x;
    if (i < N) dinv[i] = rsqrtf((float)(cnt[i] + 1u));
}

// ------- hs = bf16( (x @ W) * dinv[row] )  — dinv folded into GEMM ---------
__global__ __launch_bounds__(256) void k_gemm(const float* __restrict__ x,
                                              const float* __restrict__ W,
                                              const float* __restrict__ dinv,
                                              uint32_t* __restrict__ hs) {  // packed 2×bf16
    __shared__ float Ws[64 * 64];
    const int tid = threadIdx.x;
    #pragma unroll
    for (int i = 0; i < 4; ++i) {
        const int off = tid * 4 + i * 1024;
        *reinterpret_cast<float4*>(&Ws[off]) =
            *reinterpret_cast<const float4*>(&W[off]);
    }
    __syncthreads();
    const int row = blockIdx.x * 256 + tid;
    if (row >= N) return;
    const float* xr = x + (size_t)row * 64;
    float4 acc[16];
    #pragma unroll
    for (int i = 0; i < 16; ++i) acc[i] = make_float4(0.f, 0.f, 0.f, 0.f);
    for (int k = 0; k < 64; k += 4) {
        const float4 xv = *reinterpret_cast<const float4*>(xr + k);
        const float xs[4] = {xv.x, xv.y, xv.z, xv.w};
        #pragma unroll
        for (int kk = 0; kk < 4; ++kk) {
            const float s = xs[kk];
            const float4* wr = reinterpret_cast<const float4*>(&Ws[(k + kk) * 64]);
            #pragma unroll
            for (int d4 = 0; d4 < 16; ++d4) {
                const float4 w = wr[d4];
                acc[d4].x += s * w.x; acc[d4].y += s * w.y;
                acc[d4].z += s * w.z; acc[d4].w += s * w.w;
            }
        }
    }
    const float sc = dinv[row];
    uint32_t pack[32];
    #pragma unroll
    for (int i = 0; i < 16; ++i) {
        pack[2 * i]     = f2bf(acc[i].x * sc) | (f2bf(acc[i].y * sc) << 16);
        pack[2 * i + 1] = f2bf(acc[i].z * sc) | (f2bf(acc[i].w * sc) << 16);
    }
    uint4* hr = reinterpret_cast<uint4*>(hs + (size_t)row * 32);
    #pragma unroll
    for (int i = 0; i < 8; ++i) hr[i] = reinterpret_cast<const uint4*>(pack)[i];
}

// ---------------- scan: per-block reduce → block-prefix → local scan -------
__global__ __launch_bounds__(1024) void k_scanA(const uint32_t* __restrict__ cnt,
                                                uint32_t* __restrict__ partial) {
    __shared__ uint32_t ls[1024];
    const int t = threadIdx.x;
    const int i = blockIdx.x * 1024 + t;
    ls[t] = (i < N) ? cnt[i] : 0u;
    __syncthreads();
    for (int off = 512; off > 0; off >>= 1) {
        if (t < off) ls[t] += ls[t + off];
        __syncthreads();
    }
    if (t == 0) partial[blockIdx.x] = ls[0];
}

__global__ __launch_bounds__(128) void k_scanB(uint32_t* __restrict__ partial,
                                               uint32_t* __restrict__ rowptr) {
    __shared__ uint32_t ls[128];
    const int t = threadIdx.x;
    const uint32_t v = (t < NB) ? partial[t] : 0u;
    ls[t] = v;
    __syncthreads();
    for (int off = 1; off < 128; off <<= 1) {
        const uint32_t u = (t >= off) ? ls[t - off] : 0u;
        __syncthreads();
        ls[t] += u;
        __syncthreads();
    }
    if (t < NB) partial[t] = ls[t] - v;          // exclusive
    if (t == NB - 1) rowptr[N] = ls[t];          // == E
}

__global__ __launch_bounds__(1024) void k_scanC(const uint32_t* __restrict__ partial,
                                                uint32_t* __restrict__ cnt,   // becomes cursor
                                                uint32_t* __restrict__ rowptr) {
    __shared__ uint32_t ls[1024];
    const int t = threadIdx.x;
    const int i = blockIdx.x * 1024 + t;
    const uint32_t x = (i < N) ? cnt[i] : 0u;
    ls[t] = x;
    __syncthreads();
    for (int off = 1; off < 1024; off <<= 1) {
        const uint32_t v = (t >= off) ? ls[t - off] : 0u;
        __syncthreads();
        ls[t] += v;
        __syncthreads();
    }
    if (i < N) {
        const uint32_t r = partial[blockIdx.x] + ls[t] - x;  // exclusive
        rowptr[i] = r;
        cnt[i] = r;                                          // cursor copy
    }
}

// ------- XCD-bucketed CSR fill: block b → dst bucket (b&7), chunk (b>>3) ----
__global__ __launch_bounds__(256) void k_fill(const uint32_t* __restrict__ raw,
                                              const int* __restrict__ flag,
                                              uint32_t* __restrict__ cursor,
                                              uint32_t* __restrict__ csr) {
    const bool is64 = (*flag != 0);
    const int bucket = blockIdx.x & 7;
    const int chunk  = blockIdx.x >> 3;
    const int lo = bucket * BS, hi = lo + BS;
    const int e0 = chunk * ECH;
    const int e1 = min(E, e0 + ECH);
    for (int e = e0 + (int)threadIdx.x; e < e1; e += 256) {
        const int dx = load_idx(raw, is64, E + e);
        if (dx >= lo && dx < hi) {
            const int s = load_idx(raw, is64, e);
            const uint32_t pos = atomicAdd(&cursor[dx], 1u);
            csr[pos] = (uint32_t)s;
        }
    }
}

// ---- gather (4 edges/iter via 16-lane groups) + fused BN batch stats ------
// out[d] = (Σ_src hs[src] + hs[d]) · dinv[d] + b;  sums[c], sums[64+c] += col stats
__global__ __launch_bounds__(256) void k_gather_bn(const ushort* __restrict__ hs,
                                                   const float* __restrict__ dinv,
                                                   const uint32_t* __restrict__ rowptr,
                                                   const uint32_t* __restrict__ csr,
                                                   const float* __restrict__ b,
                                                   float* __restrict__ out,
                                                   double* __restrict__ sums) {
    const int lane = threadIdx.x & 63;
    const int wav  = threadIdx.x >> 6;       // 0..3
    const int g    = lane >> 4;              // edge group 0..3
    const int sub  = lane & 15;              // dim group: dims sub*4..sub*4+3
    const float4 bv = *reinterpret_cast<const float4*>(&b[sub * 4]);
    float regS[4] = {0.f, 0.f, 0.f, 0.f};
    float regQ[4] = {0.f, 0.f, 0.f, 0.f};

    for (int q = blockIdx.x; q < N / 4; q += gridDim.x) {
        const int d = q * 4 + wav;
        const uint32_t beg = rowptr[d], end = rowptr[d + 1];
        float a0, a1, a2, a3;
        {   // self-loop term, counted once (group 0)
            const uint2 v = *reinterpret_cast<const uint2*>(&hs[(size_t)d * 64 + sub * 4]);
            if (g == 0) { a0 = bfl(v.x); a1 = bfh(v.x); a2 = bfl(v.y); a3 = bfh(v.y); }
            else        { a0 = a1 = a2 = a3 = 0.f; }
        }
        for (uint32_t base = beg; base < end; base += 64) {
            const int m = (int)min(64u, end - base);
            int s_l = 0;
            if (base + (uint32_t)lane < end) s_l = (int)csr[base + lane];  // coalesced
            const int nq = (m + 3) >> 2;
            for (int jj = 0; jj < nq; ++jj) {
                const int s = __shfl(s_l, jj * 4 + g);     // per-group edge
                if (jj * 4 + g < m) {
                    const uint2 v = *reinterpret_cast<const uint2*>(&hs[(size_t)s * 64 + sub * 4]);
                    a0 += bfl(v.x); a1 += bfh(v.x); a2 += bfl(v.y); a3 += bfh(v.y);
                }
            }
        }
        // combine the 4 edge-groups (lanes sub, sub+16, sub+32, sub+48)
        a0 += __shfl_xor(a0, 16); a0 += __shfl_xor(a0, 32);
        a1 += __shfl_xor(a1, 16); a1 += __shfl_xor(a1, 32);
        a2 += __shfl_xor(a2, 16); a2 += __shfl_xor(a2, 32);
        a3 += __shfl_xor(a3, 16); a3 += __shfl_xor(a3, 32);
        if (g == 0) {
            const float dd = dinv[d];
            float4 o;
            o.x = a0 * dd + bv.x; o.y = a1 * dd + bv.y;
            o.z = a2 * dd + bv.z; o.w = a3 * dd + bv.w;
            *reinterpret_cast<float4*>(&out[(size_t)d * 64 + sub * 4]) = o;
            regS[0] += o.x; regQ[0] += o.x * o.x;
            regS[1] += o.y; regQ[1] += o.y * o.y;
            regS[2] += o.z; regQ[2] += o.z * o.z;
            regS[3] += o.w; regQ[3] += o.w * o.w;
        }
    }
    // block-level BN-stat reduce: 4 waves × (group0: 16 lanes × 4 cols)
    __shared__ float lsS[4][64], lsQ[4][64];
    if (g == 0) {
        #pragma unroll
        for (int k = 0; k < 4; ++k) {
            lsS[wav][sub * 4 + k] = regS[k];
            lsQ[wav][sub * 4 + k] = regQ[k];
        }
    }
    __syncthreads();
    const int t = threadIdx.x;
    if (t < 64) {
        const float s  = lsS[0][t] + lsS[1][t] + lsS[2][t] + lsS[3][t];
        const float qq = lsQ[0][t] + lsQ[1][t] + lsQ[2][t] + lsQ[3][t];
        atomicAdd(&sums[t], (double)s);
        atomicAdd(&sums[64 + t], (double)qq);
    }
}

__global__ __launch_bounds__(64) void k_bn_fin(const double* __restrict__ sums,
                                               const float* __restrict__ gamma,
                                               const float* __restrict__ beta,
                                               float* __restrict__ scale,
                                               float* __restrict__ shift) {
    const int c = threadIdx.x;
    const double mean = sums[c] / (double)N;
    const double var  = sums[64 + c] / (double)N - mean * mean;
    const float rstd  = (float)(1.0 / sqrt(var + (double)EPS));
    const float sc = gamma[c] * rstd;
    scale[c] = sc;
    shift[c] = beta[c] - (float)mean * sc;
}

// -------- fused BN-apply + dropout (partitionable threefry, XOR fold) + ReLU
__global__ __launch_bounds__(256) void k_bn_drop_relu(float* __restrict__ out,
                                                      const float* __restrict__ scale,
                                                      const float* __restrict__ shift) {
    const int j = blockIdx.x * 256 + threadIdx.x;
    uint32_t x0 = 0u, x1 = (uint32_t)j;
    threefry2x32_k42(x0, x1);
    const uint32_t bits = x0 ^ x1;
    const int c = j & 63;
    float v = out[j] * scale[c] + shift[c];
    const float u = __uint_as_float((bits >> 9) | 0x3F800000u) - 1.0f;
    v = (u < 0.9f) ? v * (1.0f / 0.9f) : 0.0f;
    out[j] = fmaxf(v, 0.f);
}

// ---------------------------------------------------------------------------
extern "C" void kernel_launch(void* const* d_in, const int* in_sizes, int n_in,
                              void* d_out, int out_size, void* d_ws, size_t ws_size,
                              hipStream_t stream) {
    const float*    x     = (const float*)d_in[0];
    const uint32_t* ei    = (const uint32_t*)d_in[1];
    const float*    W     = (const float*)d_in[2];
    const float*    b     = (const float*)d_in[3];
    const float*    gamma = (const float*)d_in[4];
    const float*    beta  = (const float*)d_in[5];
    float* out = (float*)d_out;

    uint32_t* hs     = (uint32_t*)d_ws;              // N*32 u32 (N×64 bf16, 12.8 MB)
    float*    dinv   = (float*)(hs + (size_t)N * 32);// N f32
    double*   sums   = (double*)(dinv + N);          // 128 f64 (8-aligned)
    float*    scale  = (float*)(sums + 128);         // 64
    float*    shift  = scale + 64;                   // 64
    int*      flag   = (int*)(shift + 64);           // 1
    uint32_t* partial = (uint32_t*)(flag + 1);       // 128
    uint32_t* cnt    = partial + 128;                // N (histogram → cursor)
    uint32_t* rowptr = cnt + N;                      // N+1
    uint32_t* csr    = rowptr + N + 1;               // E   (total ≈ 19 MB)

    const int nb256 = (N + 255) / 256;               // 391

    k_detect<<<1, 64, 0, stream>>>(ei, flag);
    k_zero<<<nb256, 256, 0, stream>>>(cnt, sums);
    k_hist<<<8 * HIST_CHUNKS, 256, 0, stream>>>(ei, flag, cnt);
    k_dinv<<<nb256, 256, 0, stream>>>(cnt, dinv);
    k_gemm<<<nb256, 256, 0, stream>>>(x, W, dinv, hs);
    k_scanA<<<NB, 1024, 0, stream>>>(cnt, partial);
    k_scanB<<<1, 128, 0, stream>>>(partial, rowptr);
    k_scanC<<<NB, 1024, 0, stream>>>(partial, cnt, rowptr);
    k_fill<<<8 * FILL_CHUNKS, 256, 0, stream>>>(ei, flag, cnt, csr);
    k_gather_bn<<<2048, 256, 0, stream>>>((const ushort*)hs, dinv, rowptr, csr, b, out, sums);
    k_bn_fin<<<1, 64, 0, stream>>>(sums, gamma, beta, scale, shift);
    k_bn_drop_relu<<<(N * D) / 256, 256, 0, stream>>>(out, scale, shift);
}

// Round 9
// 318.515 us; speedup vs baseline: 1.6421x; 1.0324x over previous
//
#include <hip/hip_runtime.h>
#include <cstdint>

static constexpr int N = 100000;
static constexpr int D = 64;
static constexpr int E = 1250000;
static constexpr int NB = (N + 1023) / 1024;   // 98 scan blocks
static constexpr int BS = 12500;               // dst bucket size (N/8)
static constexpr int FILL_CHUNKS = 256;
static constexpr int ECH = (E + FILL_CHUNKS - 1) / FILL_CHUNKS;  // 4883
static constexpr float EPS = 1e-5f;

// ---------------- threefry2x32, 20 rounds, key = (0, 42) --------------------
__device__ __forceinline__ uint32_t rotl32(uint32_t x, int r) {
    return (x << r) | (x >> (32 - r));
}

__device__ __forceinline__ void threefry2x32_k42(uint32_t& x0, uint32_t& x1) {
    const uint32_t ks0 = 0u, ks1 = 42u, ks2 = 0x1BD11BDAu ^ 0u ^ 42u;
    x0 += ks0; x1 += ks1;
#define TF_R4(a,b,c,d) \
    x0 += x1; x1 = rotl32(x1,a); x1 ^= x0; \
    x0 += x1; x1 = rotl32(x1,b); x1 ^= x0; \
    x0 += x1; x1 = rotl32(x1,c); x1 ^= x0; \
    x0 += x1; x1 = rotl32(x1,d); x1 ^= x0;
    TF_R4(13,15,26,6);  x0 += ks1; x1 += ks2 + 1u;
    TF_R4(17,29,16,24); x0 += ks2; x1 += ks0 + 2u;
    TF_R4(13,15,26,6);  x0 += ks0; x1 += ks1 + 3u;
    TF_R4(17,29,16,24); x0 += ks1; x1 += ks2 + 4u;
    TF_R4(13,15,26,6);  x0 += ks2; x1 += ks0 + 5u;
#undef TF_R4
}

// ---------------- bf16 helpers ---------------------------------------------
__device__ __forceinline__ uint32_t f2bf(float f) {          // RNE
    const uint32_t u = __float_as_uint(f);
    return (u + 0x7FFFu + ((u >> 16) & 1u)) >> 16;
}
__device__ __forceinline__ float bfl(uint32_t u) { return __uint_as_float(u << 16); }
__device__ __forceinline__ float bfh(uint32_t u) { return __uint_as_float(u & 0xFFFF0000u); }

__device__ __forceinline__ int load_idx(const uint32_t* raw, bool is64, int i) {
    return (int)(is64 ? raw[2u * (uint32_t)i] : raw[(uint32_t)i]);
}

// ------- zero cnt/sums + parallel int64-detect (wave 0, ballot) ------------
__global__ __launch_bounds__(256) void k_zero(const uint32_t* __restrict__ raw,
                                              uint32_t* __restrict__ cnt,
                                              double* __restrict__ sums,
                                              int* __restrict__ flag) {
    const int i = blockIdx.x * 256 + threadIdx.x;
    if (i < N) cnt[i] = 0u;
    if (blockIdx.x == 0) {
        if (threadIdx.x < 128) sums[threadIdx.x] = 0.0;
        if (threadIdx.x < 64) {
            bool ok = true;
            #pragma unroll
            for (int k = 0; k < 4; ++k)
                ok &= (raw[(threadIdx.x * 4 + k) * 2 + 1] == 0u);
            const unsigned long long m = __ballot(ok);
            if (threadIdx.x == 0) *flag = (m == ~0ULL) ? 1 : 0;
        }
    }
}

// ------- one pass: int64→int32 convert + in-degree histogram ---------------
__global__ __launch_bounds__(256) void k_prep(const uint32_t* __restrict__ raw,
                                              const int* __restrict__ flag,
                                              uint32_t* __restrict__ src32,
                                              uint32_t* __restrict__ dst32,
                                              uint32_t* __restrict__ cnt) {
    const bool is64 = (*flag != 0);
    for (int e = blockIdx.x * 256 + threadIdx.x; e < E; e += gridDim.x * 256) {
        const uint32_t s = (uint32_t)load_idx(raw, is64, e);
        const uint32_t d = (uint32_t)load_idx(raw, is64, E + e);
        src32[e] = s;
        dst32[e] = d;
        atomicAdd(&cnt[d], 1u);
    }
}

// ------- hs = bf16( (x @ W) * dinv[row] )  — dinv folded into GEMM ---------
__global__ __launch_bounds__(256) void k_gemm(const float* __restrict__ x,
                                              const float* __restrict__ W,
                                              const float* __restrict__ dinv,
                                              uint32_t* __restrict__ hs) {  // packed 2×bf16
    __shared__ float Ws[64 * 64];
    const int tid = threadIdx.x;
    #pragma unroll
    for (int i = 0; i < 4; ++i) {
        const int off = tid * 4 + i * 1024;
        *reinterpret_cast<float4*>(&Ws[off]) =
            *reinterpret_cast<const float4*>(&W[off]);
    }
    __syncthreads();
    const int row = blockIdx.x * 256 + tid;
    if (row >= N) return;
    const float* xr = x + (size_t)row * 64;
    float4 acc[16];
    #pragma unroll
    for (int i = 0; i < 16; ++i) acc[i] = make_float4(0.f, 0.f, 0.f, 0.f);
    for (int k = 0; k < 64; k += 4) {
        const float4 xv = *reinterpret_cast<const float4*>(xr + k);
        const float xs[4] = {xv.x, xv.y, xv.z, xv.w};
        #pragma unroll
        for (int kk = 0; kk < 4; ++kk) {
            const float s = xs[kk];
            const float4* wr = reinterpret_cast<const float4*>(&Ws[(k + kk) * 64]);
            #pragma unroll
            for (int d4 = 0; d4 < 16; ++d4) {
                const float4 w = wr[d4];
                acc[d4].x += s * w.x; acc[d4].y += s * w.y;
                acc[d4].z += s * w.z; acc[d4].w += s * w.w;
            }
        }
    }
    const float sc = dinv[row];
    uint32_t pack[32];
    #pragma unroll
    for (int i = 0; i < 16; ++i) {
        pack[2 * i]     = f2bf(acc[i].x * sc) | (f2bf(acc[i].y * sc) << 16);
        pack[2 * i + 1] = f2bf(acc[i].z * sc) | (f2bf(acc[i].w * sc) << 16);
    }
    uint4* hr = reinterpret_cast<uint4*>(hs + (size_t)row * 32);
    #pragma unroll
    for (int i = 0; i < 8; ++i) hr[i] = reinterpret_cast<const uint4*>(pack)[i];
}

// ------- scanA (block reduce) + fused dinv = rsqrt(cnt+1) ------------------
__global__ __launch_bounds__(1024) void k_scanA(const uint32_t* __restrict__ cnt,
                                                uint32_t* __restrict__ partial,
                                                float* __restrict__ dinv) {
    __shared__ uint32_t ls[1024];
    const int t = threadIdx.x;
    const int i = blockIdx.x * 1024 + t;
    const uint32_t c = (i < N) ? cnt[i] : 0u;
    if (i < N) dinv[i] = rsqrtf((float)(c + 1u));
    ls[t] = c;
    __syncthreads();
    for (int off = 512; off > 0; off >>= 1) {
        if (t < off) ls[t] += ls[t + off];
        __syncthreads();
    }
    if (t == 0) partial[blockIdx.x] = ls[0];
}

__global__ __launch_bounds__(128) void k_scanB(uint32_t* __restrict__ partial,
                                               uint32_t* __restrict__ rowptr) {
    __shared__ uint32_t ls[128];
    const int t = threadIdx.x;
    const uint32_t v = (t < NB) ? partial[t] : 0u;
    ls[t] = v;
    __syncthreads();
    for (int off = 1; off < 128; off <<= 1) {
        const uint32_t u = (t >= off) ? ls[t - off] : 0u;
        __syncthreads();
        ls[t] += u;
        __syncthreads();
    }
    if (t < NB) partial[t] = ls[t] - v;          // exclusive
    if (t == NB - 1) rowptr[N] = ls[t];          // == E
}

__global__ __launch_bounds__(1024) void k_scanC(const uint32_t* __restrict__ partial,
                                                uint32_t* __restrict__ cnt,   // becomes cursor
                                                uint32_t* __restrict__ rowptr) {
    __shared__ uint32_t ls[1024];
    const int t = threadIdx.x;
    const int i = blockIdx.x * 1024 + t;
    const uint32_t x = (i < N) ? cnt[i] : 0u;
    ls[t] = x;
    __syncthreads();
    for (int off = 1; off < 1024; off <<= 1) {
        const uint32_t v = (t >= off) ? ls[t - off] : 0u;
        __syncthreads();
        ls[t] += v;
        __syncthreads();
    }
    if (i < N) {
        const uint32_t r = partial[blockIdx.x] + ls[t] - x;  // exclusive
        rowptr[i] = r;
        cnt[i] = r;                                          // cursor copy
    }
}

// ------- XCD-bucketed CSR fill (int32 inputs) ------------------------------
__global__ __launch_bounds__(256) void k_fill(const uint32_t* __restrict__ src32,
                                              const uint32_t* __restrict__ dst32,
                                              uint32_t* __restrict__ cursor,
                                              uint32_t* __restrict__ csr) {
    const int bucket = blockIdx.x & 7;
    const int chunk  = blockIdx.x >> 3;
    const uint32_t lo = bucket * BS, hi = lo + BS;
    const int e0 = chunk * ECH;
    const int e1 = min(E, e0 + ECH);
    for (int e = e0 + (int)threadIdx.x; e < e1; e += 256) {
        const uint32_t dx = dst32[e];
        if (dx >= lo && dx < hi) {
            const uint32_t pos = atomicAdd(&cursor[dx], 1u);
            csr[pos] = src32[e];
        }
    }
}

// ---- gather: 16-lane group per dst, 4-deep batched loads, fused BN stats ---
__global__ __launch_bounds__(256) void k_gather_bn(const uint32_t* __restrict__ hsu,
                                                   const float* __restrict__ dinv,
                                                   const uint32_t* __restrict__ rowptr,
                                                   const uint32_t* __restrict__ csr,
                                                   const float* __restrict__ b,
                                                   float* __restrict__ out,
                                                   double* __restrict__ sums) {
    const int tid = threadIdx.x;
    const int grp = tid >> 4;            // 0..15: one dst node per group
    const int sub = tid & 15;            // dims sub*4 .. sub*4+3
    const float4 bv = *reinterpret_cast<const float4*>(&b[sub * 4]);
    float regS[4] = {0.f, 0.f, 0.f, 0.f};
    float regQ[4] = {0.f, 0.f, 0.f, 0.f};

    for (int q = blockIdx.x; q < N / 16; q += gridDim.x) {
        const int d = q * 16 + grp;
        const uint32_t beg = rowptr[d], end = rowptr[d + 1];
        const uint2 sv = *reinterpret_cast<const uint2*>(&hsu[(size_t)d * 32 + sub * 2]);
        float a0 = bfl(sv.x), a1 = bfh(sv.x), a2 = bfl(sv.y), a3 = bfh(sv.y);
        uint32_t j = beg;
        for (; j + 4 <= end; j += 4) {                       // 4 independent row loads
            const uint32_t s0 = csr[j], s1 = csr[j + 1], s2 = csr[j + 2], s3 = csr[j + 3];
            const uint2 v0 = *reinterpret_cast<const uint2*>(&hsu[(size_t)s0 * 32 + sub * 2]);
            const uint2 v1 = *reinterpret_cast<const uint2*>(&hsu[(size_t)s1 * 32 + sub * 2]);
            const uint2 v2 = *reinterpret_cast<const uint2*>(&hsu[(size_t)s2 * 32 + sub * 2]);
            const uint2 v3 = *reinterpret_cast<const uint2*>(&hsu[(size_t)s3 * 32 + sub * 2]);
            a0 += bfl(v0.x) + bfl(v1.x) + bfl(v2.x) + bfl(v3.x);
            a1 += bfh(v0.x) + bfh(v1.x) + bfh(v2.x) + bfh(v3.x);
            a2 += bfl(v0.y) + bfl(v1.y) + bfl(v2.y) + bfl(v3.y);
            a3 += bfh(v0.y) + bfh(v1.y) + bfh(v2.y) + bfh(v3.y);
        }
        for (; j < end; ++j) {
            const uint32_t s = csr[j];
            const uint2 vv = *reinterpret_cast<const uint2*>(&hsu[(size_t)s * 32 + sub * 2]);
            a0 += bfl(vv.x); a1 += bfh(vv.x); a2 += bfl(vv.y); a3 += bfh(vv.y);
        }
        const float dd = dinv[d];
        float4 o;
        o.x = a0 * dd + bv.x; o.y = a1 * dd + bv.y;
        o.z = a2 * dd + bv.z; o.w = a3 * dd + bv.w;
        *reinterpret_cast<float4*>(&out[(size_t)d * 64 + sub * 4]) = o;
        regS[0] += o.x; regQ[0] += o.x * o.x;
        regS[1] += o.y; regQ[1] += o.y * o.y;
        regS[2] += o.z; regQ[2] += o.z * o.z;
        regS[3] += o.w; regQ[3] += o.w * o.w;
    }
    __shared__ float lsS[16][64], lsQ[16][64];
    #pragma unroll
    for (int k = 0; k < 4; ++k) {
        lsS[grp][sub * 4 + k] = regS[k];
        lsQ[grp][sub * 4 + k] = regQ[k];
    }
    __syncthreads();
    if (tid < 64) {
        float s = 0.f, qq = 0.f;
        #pragma unroll
        for (int g2 = 0; g2 < 16; ++g2) { s += lsS[g2][tid]; qq += lsQ[g2][tid]; }
        atomicAdd(&sums[tid], (double)s);
        atomicAdd(&sums[64 + tid], (double)qq);
    }
}

// ---- fused BN-finalize + BN-apply + dropout (threefry, XOR fold) + ReLU ----
__global__ __launch_bounds__(256) void k_bn_drop_relu(float* __restrict__ out,
                                                      const double* __restrict__ sums,
                                                      const float* __restrict__ gamma,
                                                      const float* __restrict__ beta) {
    __shared__ float ls_sc[64], ls_sh[64];
    const int tid = threadIdx.x;
    if (tid < 64) {
        const double mean = sums[tid] / (double)N;
        const double var  = sums[64 + tid] / (double)N - mean * mean;
        const float rstd  = (float)(1.0 / sqrt(var + (double)EPS));
        const float sc = gamma[tid] * rstd;
        ls_sc[tid] = sc;
        ls_sh[tid] = beta[tid] - (float)mean * sc;
    }
    __syncthreads();
    const int base = (blockIdx.x * 256 + tid) * 2;    // grid covers N*D/2 threads
    uint32_t p0 = 0u, p1 = (uint32_t)base;
    threefry2x32_k42(p0, p1);
    const uint32_t bits0 = p0 ^ p1;
    uint32_t q0 = 0u, q1 = (uint32_t)(base + 1);
    threefry2x32_k42(q0, q1);
    const uint32_t bits1 = q0 ^ q1;
    const int c0 = base & 63;                          // even; c1 = c0+1
    float2 v = *reinterpret_cast<const float2*>(&out[base]);
    v.x = v.x * ls_sc[c0]     + ls_sh[c0];
    v.y = v.y * ls_sc[c0 + 1] + ls_sh[c0 + 1];
    const float u0 = __uint_as_float((bits0 >> 9) | 0x3F800000u) - 1.0f;
    const float u1 = __uint_as_float((bits1 >> 9) | 0x3F800000u) - 1.0f;
    v.x = (u0 < 0.9f) ? v.x * (1.0f / 0.9f) : 0.0f;
    v.y = (u1 < 0.9f) ? v.y * (1.0f / 0.9f) : 0.0f;
    v.x = fmaxf(v.x, 0.f);
    v.y = fmaxf(v.y, 0.f);
    *reinterpret_cast<float2*>(&out[base]) = v;
}

// ---------------------------------------------------------------------------
extern "C" void kernel_launch(void* const* d_in, const int* in_sizes, int n_in,
                              void* d_out, int out_size, void* d_ws, size_t ws_size,
                              hipStream_t stream) {
    const float*    x     = (const float*)d_in[0];
    const uint32_t* ei    = (const uint32_t*)d_in[1];
    const float*    W     = (const float*)d_in[2];
    const float*    b     = (const float*)d_in[3];
    const float*    gamma = (const float*)d_in[4];
    const float*    beta  = (const float*)d_in[5];
    float* out = (float*)d_out;

    uint32_t* hs      = (uint32_t*)d_ws;               // N*32 u32 (bf16 rows, 12.8 MB)
    float*    dinv    = (float*)(hs + (size_t)N * 32); // N f32
    double*   sums    = (double*)(dinv + N);           // 128 f64 (byte 13,200,000 — 8-aligned)
    int*      flag    = (int*)(sums + 128);            // 1
    uint32_t* partial = (uint32_t*)(flag + 1);         // 128
    uint32_t* cnt     = partial + 128;                 // N (hist → cursor)
    uint32_t* rowptr  = cnt + N;                       // N+1
    uint32_t* csr     = rowptr + N + 1;                // E
    uint32_t* src32   = csr + E;                       // E
    uint32_t* dst32   = src32 + E;                     // E   (total ≈ 29 MB)

    const int nb256 = (N + 255) / 256;                 // 391

    k_zero<<<nb256, 256, 0, stream>>>(ei, cnt, sums, flag);
    k_prep<<<2048, 256, 0, stream>>>(ei, flag, src32, dst32, cnt);
    k_scanA<<<NB, 1024, 0, stream>>>(cnt, partial, dinv);
    k_scanB<<<1, 128, 0, stream>>>(partial, rowptr);
    k_scanC<<<NB, 1024, 0, stream>>>(partial, cnt, rowptr);
    k_gemm<<<nb256, 256, 0, stream>>>(x, W, dinv, hs);
    k_fill<<<8 * FILL_CHUNKS, 256, 0, stream>>>(src32, dst32, cnt, csr);
    k_gather_bn<<<2048, 256, 0, stream>>>(hs, dinv, rowptr, csr, b, out, sums);
    k_bn_drop_relu<<<(N * D) / 512, 256, 0, stream>>>(out, sums, gamma, beta);
}

// Round 10
// 309.672 us; speedup vs baseline: 1.6890x; 1.0286x over previous
//
#include <hip/hip_runtime.h>
#include <cstdint>

static constexpr int N = 100000;
static constexpr int D = 64;
static constexpr int E = 1250000;
static constexpr int NB = (N + 1023) / 1024;   // 98 scan blocks
static constexpr int BS = 12500;               // dst bucket size (N/8)
static constexpr int FILL_CHUNKS = 256;
static constexpr int ECH = (E + FILL_CHUNKS - 1) / FILL_CHUNKS;  // 4883
static constexpr int NQ = N / 32;              // 3125 gather node-quads
static constexpr int GGRID = 1563;             // gather grid: 2 balanced iters
static constexpr float EPS = 1e-5f;

// ---------------- threefry2x32, 20 rounds, key = (0, 42) --------------------
__device__ __forceinline__ uint32_t rotl32(uint32_t x, int r) {
    return (x << r) | (x >> (32 - r));
}

__device__ __forceinline__ void threefry2x32_k42(uint32_t& x0, uint32_t& x1) {
    const uint32_t ks0 = 0u, ks1 = 42u, ks2 = 0x1BD11BDAu ^ 0u ^ 42u;
    x0 += ks0; x1 += ks1;
#define TF_R4(a,b,c,d) \
    x0 += x1; x1 = rotl32(x1,a); x1 ^= x0; \
    x0 += x1; x1 = rotl32(x1,b); x1 ^= x0; \
    x0 += x1; x1 = rotl32(x1,c); x1 ^= x0; \
    x0 += x1; x1 = rotl32(x1,d); x1 ^= x0;
    TF_R4(13,15,26,6);  x0 += ks1; x1 += ks2 + 1u;
    TF_R4(17,29,16,24); x0 += ks2; x1 += ks0 + 2u;
    TF_R4(13,15,26,6);  x0 += ks0; x1 += ks1 + 3u;
    TF_R4(17,29,16,24); x0 += ks1; x1 += ks2 + 4u;
    TF_R4(13,15,26,6);  x0 += ks2; x1 += ks0 + 5u;
#undef TF_R4
}

// ---------------- bf16 helpers ---------------------------------------------
__device__ __forceinline__ uint32_t f2bf(float f) {          // RNE
    const uint32_t u = __float_as_uint(f);
    return (u + 0x7FFFu + ((u >> 16) & 1u)) >> 16;
}
__device__ __forceinline__ float bfl(uint32_t u) { return __uint_as_float(u << 16); }
__device__ __forceinline__ float bfh(uint32_t u) { return __uint_as_float(u & 0xFFFF0000u); }

__device__ __forceinline__ int load_idx(const uint32_t* raw, bool is64, int i) {
    return (int)(is64 ? raw[2u * (uint32_t)i] : raw[(uint32_t)i]);
}

// ------- zero cnt + sums + dh + dcur (contiguous u32 span) -----------------
__global__ __launch_bounds__(256) void k_zero(uint32_t* __restrict__ z, int n32) {
    const int i = blockIdx.x * 256 + threadIdx.x;
    if (i < n32) z[i] = 0u;
}

// ------- one pass: self-detect dtype + int64→int32 + in-degree histogram ---
__global__ __launch_bounds__(256) void k_prep(const uint32_t* __restrict__ raw,
                                              uint32_t* __restrict__ src32,
                                              uint32_t* __restrict__ dst32,
                                              uint32_t* __restrict__ cnt) {
    __shared__ int s_is64;
    if (threadIdx.x < 64) {
        bool ok = true;
        #pragma unroll
        for (int k = 0; k < 4; ++k)
            ok &= (raw[(threadIdx.x * 4 + k) * 2 + 1] == 0u);
        const unsigned long long m = __ballot(ok);
        if (threadIdx.x == 0) s_is64 = (m == ~0ULL) ? 1 : 0;
    }
    __syncthreads();
    const bool is64 = (s_is64 != 0);
    for (int e = blockIdx.x * 256 + threadIdx.x; e < E; e += gridDim.x * 256) {
        const uint32_t s = (uint32_t)load_idx(raw, is64, e);
        const uint32_t d = (uint32_t)load_idx(raw, is64, E + e);
        src32[e] = s;
        dst32[e] = d;
        atomicAdd(&cnt[d], 1u);
    }
}

// ------- hs = bf16( (x @ W) * dinv[row] )  — dinv folded into GEMM ---------
__global__ __launch_bounds__(256) void k_gemm(const float* __restrict__ x,
                                              const float* __restrict__ W,
                                              const float* __restrict__ dinv,
                                              uint32_t* __restrict__ hs) {  // packed 2×bf16
    __shared__ float Ws[64 * 64];
    const int tid = threadIdx.x;
    #pragma unroll
    for (int i = 0; i < 4; ++i) {
        const int off = tid * 4 + i * 1024;
        *reinterpret_cast<float4*>(&Ws[off]) =
            *reinterpret_cast<const float4*>(&W[off]);
    }
    __syncthreads();
    const int row = blockIdx.x * 256 + tid;
    if (row >= N) return;
    const float* xr = x + (size_t)row * 64;
    float4 acc[16];
    #pragma unroll
    for (int i = 0; i < 16; ++i) acc[i] = make_float4(0.f, 0.f, 0.f, 0.f);
    for (int k = 0; k < 64; k += 4) {
        const float4 xv = *reinterpret_cast<const float4*>(xr + k);
        const float xs[4] = {xv.x, xv.y, xv.z, xv.w};
        #pragma unroll
        for (int kk = 0; kk < 4; ++kk) {
            const float s = xs[kk];
            const float4* wr = reinterpret_cast<const float4*>(&Ws[(k + kk) * 64]);
            #pragma unroll
            for (int d4 = 0; d4 < 16; ++d4) {
                const float4 w = wr[d4];
                acc[d4].x += s * w.x; acc[d4].y += s * w.y;
                acc[d4].z += s * w.z; acc[d4].w += s * w.w;
            }
        }
    }
    const float sc = dinv[row];
    uint32_t pack[32];
    #pragma unroll
    for (int i = 0; i < 16; ++i) {
        pack[2 * i]     = f2bf(acc[i].x * sc) | (f2bf(acc[i].y * sc) << 16);
        pack[2 * i + 1] = f2bf(acc[i].z * sc) | (f2bf(acc[i].w * sc) << 16);
    }
    uint4* hr = reinterpret_cast<uint4*>(hs + (size_t)row * 32);
    #pragma unroll
    for (int i = 0; i < 8; ++i) hr[i] = reinterpret_cast<const uint4*>(pack)[i];
}

// ------- scanA: block reduce + dinv + per-block degree histogram → dh ------
__global__ __launch_bounds__(1024) void k_scanA(const uint32_t* __restrict__ cnt,
                                                uint32_t* __restrict__ partial,
                                                float* __restrict__ dinv,
                                                uint32_t* __restrict__ dh) {
    __shared__ uint32_t ls[1024];
    __shared__ uint32_t dhist[128];
    const int t = threadIdx.x;
    if (t < 128) dhist[t] = 0u;
    __syncthreads();
    const int i = blockIdx.x * 1024 + t;
    const uint32_t c = (i < N) ? cnt[i] : 0u;
    if (i < N) {
        dinv[i] = rsqrtf((float)(c + 1u));
        atomicAdd(&dhist[min(c, 127u)], 1u);
    }
    ls[t] = c;
    __syncthreads();
    for (int off = 512; off > 0; off >>= 1) {
        if (t < off) ls[t] += ls[t + off];
        __syncthreads();
    }
    if (t == 0) partial[blockIdx.x] = ls[0];
    if (t < 128 && dhist[t] != 0u) atomicAdd(&dh[t], dhist[t]);
}

// ------- scanB: scan partials → block prefixes; scan dh → dcur -------------
__global__ __launch_bounds__(128) void k_scanB(uint32_t* __restrict__ partial,
                                               uint32_t* __restrict__ rowptr,
                                               const uint32_t* __restrict__ dh,
                                               uint32_t* __restrict__ dcur) {
    __shared__ uint32_t ls[128];
    const int t = threadIdx.x;
    const uint32_t v = (t < NB) ? partial[t] : 0u;
    ls[t] = v;
    __syncthreads();
    for (int off = 1; off < 128; off <<= 1) {
        const uint32_t u = (t >= off) ? ls[t - off] : 0u;
        __syncthreads();
        ls[t] += u;
        __syncthreads();
    }
    if (t < NB) partial[t] = ls[t] - v;          // exclusive
    if (t == NB - 1) rowptr[N] = ls[t];          // == E
    __syncthreads();
    const uint32_t hv = dh[t];
    ls[t] = hv;
    __syncthreads();
    for (int off = 1; off < 128; off <<= 1) {
        const uint32_t u = (t >= off) ? ls[t - off] : 0u;
        __syncthreads();
        ls[t] += u;
        __syncthreads();
    }
    dcur[t] = ls[t] - hv;                        // exclusive degree-bucket start
}

__global__ __launch_bounds__(1024) void k_scanC(const uint32_t* __restrict__ partial,
                                                uint32_t* __restrict__ cnt,   // becomes cursor
                                                uint32_t* __restrict__ rowptr) {
    __shared__ uint32_t ls[1024];
    const int t = threadIdx.x;
    const int i = blockIdx.x * 1024 + t;
    const uint32_t x = (i < N) ? cnt[i] : 0u;
    ls[t] = x;
    __syncthreads();
    for (int off = 1; off < 1024; off <<= 1) {
        const uint32_t v = (t >= off) ? ls[t - off] : 0u;
        __syncthreads();
        ls[t] += v;
        __syncthreads();
    }
    if (i < N) {
        const uint32_t r = partial[blockIdx.x] + ls[t] - x;  // exclusive
        rowptr[i] = r;
        cnt[i] = r;                                          // cursor copy
    }
}

// ------- counting-sort nodes by degree → perm (unstable, LDS-aggregated) ---
__global__ __launch_bounds__(256) void k_perm(const uint32_t* __restrict__ rowptr,
                                              uint32_t* __restrict__ dcur,
                                              uint32_t* __restrict__ perm) {
    __shared__ uint32_t lcnt[128], lbase[128];
    const int tid = threadIdx.x;
    if (tid < 128) lcnt[tid] = 0u;
    __syncthreads();
    const int i = blockIdx.x * 256 + tid;
    int d = 0; uint32_t lrank = 0;
    if (i < N) {
        d = (int)min(rowptr[i + 1] - rowptr[i], 127u);
        lrank = atomicAdd(&lcnt[d], 1u);
    }
    __syncthreads();
    if (tid < 128 && lcnt[tid] != 0u) lbase[tid] = atomicAdd(&dcur[tid], lcnt[tid]);
    __syncthreads();
    if (i < N) perm[lbase[d] + lrank] = (uint32_t)i;
}

// ------- XCD-bucketed CSR fill (int32 inputs) ------------------------------
__global__ __launch_bounds__(256) void k_fill(const uint32_t* __restrict__ src32,
                                              const uint32_t* __restrict__ dst32,
                                              uint32_t* __restrict__ cursor,
                                              uint32_t* __restrict__ csr) {
    const int bucket = blockIdx.x & 7;
    const int chunk  = blockIdx.x >> 3;
    const uint32_t lo = bucket * BS, hi = lo + BS;
    const int e0 = chunk * ECH;
    const int e1 = min(E, e0 + ECH);
    for (int e = e0 + (int)threadIdx.x; e < e1; e += 256) {
        const uint32_t dx = dst32[e];
        if (dx >= lo && dx < hi) {
            const uint32_t pos = atomicAdd(&cursor[dx], 1u);
            csr[pos] = src32[e];
        }
    }
}

// ---- gather: 8-lane group/dst, depth-8 batches, degree-sorted, fused BN ---
__global__ __launch_bounds__(256) void k_gather_bn(const uint32_t* __restrict__ hsu,
                                                   const float* __restrict__ dinv,
                                                   const uint32_t* __restrict__ rowptr,
                                                   const uint32_t* __restrict__ csr,
                                                   const uint32_t* __restrict__ perm,
                                                   const float* __restrict__ b,
                                                   float* __restrict__ out,
                                                   double* __restrict__ sums) {
    const int tid = threadIdx.x;
    const int grp = tid >> 3;            // 0..31: one dst node per 8-lane group
    const int sub = tid & 7;             // dims sub*8 .. sub*8+7
    float bb[8];
    {
        const float4 b0 = *reinterpret_cast<const float4*>(&b[sub * 8]);
        const float4 b1 = *reinterpret_cast<const float4*>(&b[sub * 8 + 4]);
        bb[0] = b0.x; bb[1] = b0.y; bb[2] = b0.z; bb[3] = b0.w;
        bb[4] = b1.x; bb[5] = b1.y; bb[6] = b1.z; bb[7] = b1.w;
    }
    float regS[8], regQ[8];
    #pragma unroll
    for (int k = 0; k < 8; ++k) { regS[k] = 0.f; regQ[k] = 0.f; }

    for (int q = blockIdx.x; q < NQ; q += GGRID) {       // ≤2 balanced iters
        const int d = (int)perm[q * 32 + grp];
        const uint32_t beg = rowptr[d], end = rowptr[d + 1];
        float a[8];
        {
            const uint4 sv = *reinterpret_cast<const uint4*>(&hsu[(size_t)d * 32 + sub * 4]);
            a[0] = bfl(sv.x); a[1] = bfh(sv.x); a[2] = bfl(sv.y); a[3] = bfh(sv.y);
            a[4] = bfl(sv.z); a[5] = bfh(sv.z); a[6] = bfl(sv.w); a[7] = bfh(sv.w);
        }
        uint32_t j = beg;
        while (j + 8 <= end) {                           // depth-8 batches
            const uint32_t sj = csr[j + (uint32_t)sub];  // 8 lanes: 8 edge ids
            uint4 v[8];
            #pragma unroll
            for (int k = 0; k < 8; ++k) {
                const int s = __shfl((int)sj, k, 8);     // group-local broadcast
                v[k] = *reinterpret_cast<const uint4*>(&hsu[(size_t)s * 32 + sub * 4]);
            }
            #pragma unroll
            for (int k = 0; k < 8; ++k) {
                a[0] += bfl(v[k].x); a[1] += bfh(v[k].x);
                a[2] += bfl(v[k].y); a[3] += bfh(v[k].y);
                a[4] += bfl(v[k].z); a[5] += bfh(v[k].z);
                a[6] += bfl(v[k].w); a[7] += bfh(v[k].w);
            }
            j += 8;
        }
        if (j < end) {                                   // tail < 8
            const uint32_t sj = (j + (uint32_t)sub < end) ? csr[j + (uint32_t)sub] : 0u;
            const int r = (int)(end - j);
            for (int k = 0; k < r; ++k) {
                const int s = __shfl((int)sj, k, 8);
                const uint4 vv = *reinterpret_cast<const uint4*>(&hsu[(size_t)s * 32 + sub * 4]);
                a[0] += bfl(vv.x); a[1] += bfh(vv.x);
                a[2] += bfl(vv.y); a[3] += bfh(vv.y);
                a[4] += bfl(vv.z); a[5] += bfh(vv.z);
                a[6] += bfl(vv.w); a[7] += bfh(vv.w);
            }
        }
        const float dd = dinv[d];
        float o[8];
        #pragma unroll
        for (int k = 0; k < 8; ++k) {
            o[k] = a[k] * dd + bb[k];
            regS[k] += o[k]; regQ[k] += o[k] * o[k];
        }
        const float4 o0 = make_float4(o[0], o[1], o[2], o[3]);
        const float4 o1 = make_float4(o[4], o[5], o[6], o[7]);
        *reinterpret_cast<float4*>(&out[(size_t)d * 64 + sub * 8])     = o0;
        *reinterpret_cast<float4*>(&out[(size_t)d * 64 + sub * 8 + 4]) = o1;
    }
    __shared__ float lsS[32][64], lsQ[32][64];
    #pragma unroll
    for (int k = 0; k < 8; ++k) {
        lsS[grp][sub * 8 + k] = regS[k];
        lsQ[grp][sub * 8 + k] = regQ[k];
    }
    __syncthreads();
    if (tid < 64) {
        float s = 0.f, qq = 0.f;
        #pragma unroll
        for (int g2 = 0; g2 < 32; ++g2) { s += lsS[g2][tid]; qq += lsQ[g2][tid]; }
        atomicAdd(&sums[tid], (double)s);
        atomicAdd(&sums[64 + tid], (double)qq);
    }
}

// ---- fused BN-finalize + BN-apply + dropout (threefry, XOR fold) + ReLU ----
__global__ __launch_bounds__(256) void k_bn_drop_relu(float* __restrict__ out,
                                                      const double* __restrict__ sums,
                                                      const float* __restrict__ gamma,
                                                      const float* __restrict__ beta) {
    __shared__ float ls_sc[64], ls_sh[64];
    const int tid = threadIdx.x;
    if (tid < 64) {
        const double mean = sums[tid] / (double)N;
        const double var  = sums[64 + tid] / (double)N - mean * mean;
        const float rstd  = (float)(1.0 / sqrt(var + (double)EPS));
        const float sc = gamma[tid] * rstd;
        ls_sc[tid] = sc;
        ls_sh[tid] = beta[tid] - (float)mean * sc;
    }
    __syncthreads();
    const int base = (blockIdx.x * 256 + tid) * 2;    // grid covers N*D/2 threads
    uint32_t p0 = 0u, p1 = (uint32_t)base;
    threefry2x32_k42(p0, p1);
    const uint32_t bits0 = p0 ^ p1;
    uint32_t q0 = 0u, q1 = (uint32_t)(base + 1);
    threefry2x32_k42(q0, q1);
    const uint32_t bits1 = q0 ^ q1;
    const int c0 = base & 63;                          // even; c1 = c0+1
    float2 v = *reinterpret_cast<const float2*>(&out[base]);
    v.x = v.x * ls_sc[c0]     + ls_sh[c0];
    v.y = v.y * ls_sc[c0 + 1] + ls_sh[c0 + 1];
    const float u0 = __uint_as_float((bits0 >> 9) | 0x3F800000u) - 1.0f;
    const float u1 = __uint_as_float((bits1 >> 9) | 0x3F800000u) - 1.0f;
    v.x = (u0 < 0.9f) ? v.x * (1.0f / 0.9f) : 0.0f;
    v.y = (u1 < 0.9f) ? v.y * (1.0f / 0.9f) : 0.0f;
    v.x = fmaxf(v.x, 0.f);
    v.y = fmaxf(v.y, 0.f);
    *reinterpret_cast<float2*>(&out[base]) = v;
}

// ---------------------------------------------------------------------------
extern "C" void kernel_launch(void* const* d_in, const int* in_sizes, int n_in,
                              void* d_out, int out_size, void* d_ws, size_t ws_size,
                              hipStream_t stream) {
    const float*    x     = (const float*)d_in[0];
    const uint32_t* ei    = (const uint32_t*)d_in[1];
    const float*    W     = (const float*)d_in[2];
    const float*    b     = (const float*)d_in[3];
    const float*    gamma = (const float*)d_in[4];
    const float*    beta  = (const float*)d_in[5];
    float* out = (float*)d_out;

    uint32_t* hs      = (uint32_t*)d_ws;               // N*32 u32 (bf16 rows, 12.8 MB)
    float*    dinv    = (float*)(hs + (size_t)N * 32); // N f32
    double*   sums    = (double*)(dinv + N);           // 128 f64 (8-aligned)
    uint32_t* dh      = (uint32_t*)(sums + 128);       // 128 (degree histogram)
    uint32_t* dcur    = dh + 128;                      // 128 (bucket cursors)
    uint32_t* cnt     = dcur + 128;                    // N (hist → CSR cursor)
    uint32_t* partial = cnt + N;                       // 128
    uint32_t* rowptr  = partial + 128;                 // N+1
    uint32_t* perm    = rowptr + N + 1;                // N
    uint32_t* csr     = perm + N;                      // E
    uint32_t* src32   = csr + E;                       // E
    uint32_t* dst32   = src32 + E;                     // E   (total ≈ 30 MB)

    const int nb256 = (N + 255) / 256;                 // 391
    // zero span: sums(256 u32) + dh(128) + dcur(128) + cnt(N)
    const int nz = 256 + 128 + 128 + N;

    k_zero<<<(nz + 255) / 256, 256, 0, stream>>>((uint32_t*)sums, nz);
    k_prep<<<2048, 256, 0, stream>>>(ei, src32, dst32, cnt);
    k_scanA<<<NB, 1024, 0, stream>>>(cnt, partial, dinv, dh);
    k_scanB<<<1, 128, 0, stream>>>(partial, rowptr, dh, dcur);
    k_scanC<<<NB, 1024, 0, stream>>>(partial, cnt, rowptr);
    k_perm<<<nb256, 256, 0, stream>>>(rowptr, dcur, perm);
    k_gemm<<<nb256, 256, 0, stream>>>(x, W, dinv, hs);
    k_fill<<<8 * FILL_CHUNKS, 256, 0, stream>>>(src32, dst32, cnt, csr);
    k_gather_bn<<<GGRID, 256, 0, stream>>>(hs, dinv, rowptr, csr, perm, b, out, sums);
    k_bn_drop_relu<<<(N * D) / 512, 256, 0, stream>>>(out, sums, gamma, beta);
}